// Round 11
// baseline (231.979 us; speedup 1.0000x reference)
//
#include <hip/hip_runtime.h>
#include <hip/hip_bf16.h>

#define B_ 256
#define L_ 225
#define D_ 1280
#define H_ 256
#define U_ 256
#define LT 45     // real rows per block-tile (5 * 45 = 225 exact)
#define LTP 48    // padded rows computed (3 MFMA row-frags)

typedef __bf16  bf16x8 __attribute__((ext_vector_type(8)));
typedef float   f32x4  __attribute__((ext_vector_type(4)));
typedef unsigned short u16x8 __attribute__((ext_vector_type(8)));
typedef unsigned short u16x4 __attribute__((ext_vector_type(4)));

__device__ __forceinline__ unsigned short f2bf(float f) {
    union { __hip_bfloat16 h; unsigned short u; } cv;
    cv.h = __float2bfloat16(f);   // RNE
    return cv.u;
}

__device__ __forceinline__ u16x4 cvt4(f32x4 v) {
    u16x4 q;
    q[0] = f2bf(v[0]); q[1] = f2bf(v[1]); q[2] = f2bf(v[2]); q[3] = f2bf(v[3]);
    return q;
}

__device__ __forceinline__ f32x4 bf4_to_f32(u16x4 w) {
    union { unsigned u; float f; } a0, a1, a2, a3;
    a0.u = (unsigned)w[0] << 16; a1.u = (unsigned)w[1] << 16;
    a2.u = (unsigned)w[2] << 16; a3.u = (unsigned)w[3] << 16;
    return (f32x4){a0.f, a1.f, a2.f, a3.f};
}

__device__ __forceinline__ void gload_lds16(const void* g, void* l) {
    __builtin_amdgcn_global_load_lds(
        (const __attribute__((address_space(1))) unsigned int*)g,
        (__attribute__((address_space(3))) unsigned int*)l,
        16, 0, 0);
}

__device__ __forceinline__ float wredsum(float x) {
#pragma unroll
    for (int off = 32; off > 0; off >>= 1) x += __shfl_xor(x, off, 64);
    return x;
}

// ------ kernel 1: merged prep: W1t bf16 transpose + ph = hidden.W2+b1+b2 ----
__global__ void k_prep(const float* __restrict__ W1,
                       const float* __restrict__ hidden,
                       const float* __restrict__ W2,
                       const float* __restrict__ b1,
                       const float* __restrict__ b2,
                       __hip_bfloat16* __restrict__ w1t,
                       float* __restrict__ ph) {
    int bid = blockIdx.x;
    if (bid < 1280) {
        int idx = bid * 256 + threadIdx.x;   // idx = k*U_+u
        int k = idx / U_;
        int u = idx % U_;
        w1t[(size_t)u * D_ + k] = __float2bfloat16(W1[idx]);
    } else {
        __shared__ float sh[H_];
        int b = bid - 1280;
        int u = threadIdx.x;
        sh[u] = hidden[b * H_ + u];
        __syncthreads();
        float acc = b1[u] + b2[u];
#pragma unroll 8
        for (int h = 0; h < H_; ++h) acc += sh[h] * W2[h * U_ + u];
        ph[b * U_ + u] = acc;
    }
}

// ---------------- kernel 2: one-read fused kernel ---------------------------
// 1280 blocks (b = blk/5, tile s5 = blk%5) x 512 threads, 2 blocks/CU.
// A f32->bf16 reg-cvt; quads KEPT in 60 VGPRs (macro-unrolled K-loop: all
// hold[] indices are literals -> no scratch). B dbuf via global_load_lds.
// Context computed from register-held quads: features read from HBM ONCE.
// LDS: A0@0(6144) A1@6144 | B0@12288(32768) B1@45056 | sL@77824(1536)
//      sW@79360(192) -> 79552 B total (2 blocks/CU).
__global__ __launch_bounds__(512, 4) void k_fused(
        const float* __restrict__ feat,
        const __hip_bfloat16* __restrict__ w1t,
        const float* __restrict__ ph,
        const float* __restrict__ Vv,
        float* __restrict__ num,
        float* __restrict__ den) {
    __shared__ __align__(128) char smem[79552];
    float* sL = (float*)(smem + 77824);
    float* sW = (float*)(smem + 79360);

    const int tid  = threadIdx.x;
    const int lane = tid & 63;
    const int wave = tid >> 6;     // 0..7
    const int blk  = blockIdx.x;
    const int b    = blk / 5;
    const int s5   = blk - b * 5;

    const float* featB = feat + ((size_t)b * L_ + s5 * LT) * D_;

    const int g    = tid >> 5;     // 0..15 -> rows {3g, 3g+1, 3g+2}
    const int qw   = tid & 31;     // quad-col within each 128-col window
    const int half = qw >> 4;      // stages steps with (s&1)==half
    const int ql   = qw & 15;      // quad-col within a 64-col K-step

    const float* aRow[3];
    int aOff[3];
#pragma unroll
    for (int i = 0; i < 3; ++i) {
        int r  = 3 * g + i;
        int rc = r < LT ? r : (LT - 1);
        aRow[i] = featB + (size_t)rc * D_ + ql * 4;
        aOff[i] = r * 128 + ((ql * 8) ^ ((r & 7) << 4));
    }

    int bOff[4];    // 32-bit element offsets into w1t (saves VGPRs vs ptrs)
#pragma unroll
    for (int p = 0; p < 4; ++p) {
        int sI = p * 512 + tid;
        int u  = sI >> 3;
        int c8 = (sI & 7) ^ (u & 7);
        bOff[p] = u * D_ + c8 * 8;
    }

    u16x4 hold[10][3];             // 60 VGPRs: the block's A-tile, kept
    f32x4 acc[3][2];
#pragma unroll
    for (int mi = 0; mi < 3; ++mi)
#pragma unroll
        for (int ni = 0; ni < 2; ++ni)
            acc[mi][ni] = (f32x4){0.f, 0.f, 0.f, 0.f};

    const int u0 = wave * 32 + (lane & 15);

    auto stageB = [&](int s) {
        char* bufB = smem + 12288 + (s & 1) * 32768;
#pragma unroll
        for (int p = 0; p < 4; ++p)
            gload_lds16(w1t + bOff[p] + s * 64, bufB + p * 8192 + tid * 16);
    };
    auto compute = [&](int s) {
        const char* bufA = smem + (s & 1) * 6144;
        const char* bufB = smem + 12288 + (s & 1) * 32768;
#pragma unroll
        for (int ks = 0; ks < 2; ++ks) {
            const int kk2 = (ks * 32 + ((lane >> 4) << 3)) * 2;
            bf16x8 a[3], bb[2];
#pragma unroll
            for (int mi = 0; mi < 3; ++mi) {
                int r = mi * 16 + (lane & 15);
                a[mi] = *reinterpret_cast<const bf16x8*>(
                    bufA + r * 128 + (kk2 ^ ((r & 7) << 4)));
            }
            bb[0] = *reinterpret_cast<const bf16x8*>(
                bufB + u0 * 128 + (kk2 ^ ((u0 & 7) << 4)));
            bb[1] = *reinterpret_cast<const bf16x8*>(
                bufB + (u0 + 16) * 128 + (kk2 ^ (((u0 + 16) & 7) << 4)));
#pragma unroll
            for (int mi = 0; mi < 3; ++mi)
#pragma unroll
                for (int ni = 0; ni < 2; ++ni)
                    acc[mi][ni] = __builtin_amdgcn_mfma_f32_16x16x32_bf16(
                        a[mi], bb[ni], acc[mi][ni], 0, 0, 0);
        }
    };

    // ---- prologue: stage step 0 ----
    if (half == 0) {
        f32x4 v0q = *reinterpret_cast<const f32x4*>(aRow[0]);
        f32x4 v1q = *reinterpret_cast<const f32x4*>(aRow[1]);
        f32x4 v2q = *reinterpret_cast<const f32x4*>(aRow[2]);
        u16x4 q0 = cvt4(v0q), q1 = cvt4(v1q), q2 = cvt4(v2q);
        hold[0][0] = q0; hold[0][1] = q1; hold[0][2] = q2;
        *reinterpret_cast<u16x4*>(smem + aOff[0]) = q0;
        *reinterpret_cast<u16x4*>(smem + aOff[1]) = q1;
        *reinterpret_cast<u16x4*>(smem + aOff[2]) = q2;
    }
    stageB(0);
    __syncthreads();

    // ---- K-loop: 20 macro-expanded steps, literal constants everywhere ----
#define KSTEP(S)                                                              \
    {                                                                         \
        f32x4 v0q, v1q, v2q;                                                  \
        const bool pf = ((S) < 19) && ((((S) + 1) & 1) == half);              \
        if (pf) {                                                             \
            v0q = *reinterpret_cast<const f32x4*>(aRow[0] + ((S) + 1) * 64);  \
            v1q = *reinterpret_cast<const f32x4*>(aRow[1] + ((S) + 1) * 64);  \
            v2q = *reinterpret_cast<const f32x4*>(aRow[2] + ((S) + 1) * 64);  \
        }                                                                     \
        if ((S) < 19) stageB((S) + 1);                                        \
        compute(S);                                                           \
        if (pf) {                                                             \
            char* bufA = smem + (((S) + 1) & 1) * 6144;                       \
            u16x4 q0 = cvt4(v0q), q1 = cvt4(v1q), q2 = cvt4(v2q);             \
            hold[((S) + 1) >> 1][0] = q0;                                     \
            hold[((S) + 1) >> 1][1] = q1;                                     \
            hold[((S) + 1) >> 1][2] = q2;                                     \
            *reinterpret_cast<u16x4*>(bufA + aOff[0]) = q0;                   \
            *reinterpret_cast<u16x4*>(bufA + aOff[1]) = q1;                   \
            *reinterpret_cast<u16x4*>(bufA + aOff[2]) = q2;                   \
        }                                                                     \
        __syncthreads();                                                      \
    }
    KSTEP(0)  KSTEP(1)  KSTEP(2)  KSTEP(3)  KSTEP(4)
    KSTEP(5)  KSTEP(6)  KSTEP(7)  KSTEP(8)  KSTEP(9)
    KSTEP(10) KSTEP(11) KSTEP(12) KSTEP(13) KSTEP(14)
    KSTEP(15) KSTEP(16) KSTEP(17) KSTEP(18) KSTEP(19)
#undef KSTEP

    // ---- epilogue: tanh(acc+ph)*V -> per-wave partial logits ----
    const float* phB = ph + b * 256;
    float ph0 = phB[u0], ph1 = phB[u0 + 16];
    float v0  = Vv[u0],  v1  = Vv[u0 + 16];
#pragma unroll
    for (int mi = 0; mi < 3; ++mi) {
#pragma unroll
        for (int rg = 0; rg < 4; ++rg) {
            int row = mi * 16 + ((lane >> 4) << 2) + rg;   // 0..47
            float x0 = acc[mi][0][rg] + ph0;
            float x1 = acc[mi][1][rg] + ph1;
            float sl = (1.f - 2.f / (__expf(2.f * x0) + 1.f)) * v0
                     + (1.f - 2.f / (__expf(2.f * x1) + 1.f)) * v1;
            sl += __shfl_xor(sl, 1, 64);
            sl += __shfl_xor(sl, 2, 64);
            sl += __shfl_xor(sl, 4, 64);
            sl += __shfl_xor(sl, 8, 64);
            if ((lane & 15) == 0) sL[wave * LTP + row] = sl;
        }
    }
    __syncthreads();

    // ---- weights w = exp(logit) (no max: |logit| <= sum|V| ~ 13) ----
    if (wave == 0) {
        float w = 0.f;
        if (lane < LT) {
            float lg = 0.f;
#pragma unroll
            for (int wc = 0; wc < 8; ++wc) lg += sL[wc * LTP + lane];
            w = __expf(lg);
            sW[lane] = w;
        }
        if (lane >= LT && lane < LTP) sW[lane] = 0.f;   // pad rows
        float d = wredsum(w);
        if (lane == 0) den[blk] = d;
    }
    __syncthreads();   // sW ready; all GEMM LDS reads done -> pc may overwrite

    // ---- context from register-held A quads: zero global reads ----
    float* pc = (float*)smem;   // [8][1280] f32 = 40960 B
    const float w0 = sW[3 * g], w1 = sW[3 * g + 1], w2 = sW[3 * g + 2];
    if (g < 8) {
#pragma unroll
        for (int w = 0; w < 10; ++w) {
            f32x4 p = w0 * bf4_to_f32(hold[w][0])
                    + w1 * bf4_to_f32(hold[w][1])
                    + w2 * bf4_to_f32(hold[w][2]);
            *reinterpret_cast<f32x4*>(pc + g * 1280 + w * 128 + qw * 4) = p;
        }
    }
    __syncthreads();
    if (g >= 8) {
#pragma unroll
        for (int w = 0; w < 10; ++w) {
            f32x4 p = w0 * bf4_to_f32(hold[w][0])
                    + w1 * bf4_to_f32(hold[w][1])
                    + w2 * bf4_to_f32(hold[w][2]);
            f32x4* dst = reinterpret_cast<f32x4*>(pc + (g - 8) * 1280 + w * 128 + qw * 4);
            *dst += p;
        }
    }
    __syncthreads();
    if (tid < 320) {
        f32x4 s = (f32x4){0.f, 0.f, 0.f, 0.f};
#pragma unroll
        for (int j = 0; j < 8; ++j)
            s += *reinterpret_cast<const f32x4*>(pc + j * 1280 + (tid << 2));
        *reinterpret_cast<f32x4*>(num + (size_t)blk * 1280 + (tid << 2)) = s;
    }
}

// ---------------- kernel 3: combine 5 tile-partials per batch ----------------
__global__ void k_combine(const float* __restrict__ num, const float* __restrict__ den,
                          float* __restrict__ out) {
    int b = blockIdx.x;
    int t = threadIdx.x;   // 0..319
    f32x4 n = (f32x4){0.f, 0.f, 0.f, 0.f};
    float d = 0.f;
#pragma unroll
    for (int s = 0; s < 5; ++s) {
        n += *reinterpret_cast<const f32x4*>(num + (size_t)(b * 5 + s) * 1280 + (t << 2));
        d += den[b * 5 + s];
    }
    n *= (1.f / d);
    *reinterpret_cast<f32x4*>(out + (size_t)b * D_ + (t << 2)) = n;
}

extern "C" void kernel_launch(void* const* d_in, const int* in_sizes, int n_in,
                              void* d_out, int out_size, void* d_ws, size_t ws_size,
                              hipStream_t stream) {
    const float* feat   = (const float*)d_in[0];
    const float* hidden = (const float*)d_in[1];
    const float* W1     = (const float*)d_in[2];
    const float* b1     = (const float*)d_in[3];
    const float* W2     = (const float*)d_in[4];
    const float* b2     = (const float*)d_in[5];
    const float* Vv     = (const float*)d_in[6];
    // bV (d_in[7]) is a uniform logit shift -> softmax-invariant; skipped.

    char* ws = (char*)d_ws;
    __hip_bfloat16* w1t = (__hip_bfloat16*)(ws);    // 655360 B
    float* ph  = (float*)(ws + 655360);             // 262144 B
    float* num = (float*)(ws + 917504);             // 1280*1280*4 = 6553600 B
    float* den = (float*)(ws + 7471104);            // 5120 B
    float* out = (float*)d_out;

    k_prep   <<<1536, 256, 0, stream>>>(W1, hidden, W2, b1, b2, w1t, ph);
    k_fused  <<<B_ * 5, 512, 0, stream>>>(feat, w1t, ph, Vv, num, den);
    k_combine<<<B_, 320, 0, stream>>>(num, den, out);
}

// Round 12
// 126.839 us; speedup vs baseline: 1.8289x; 1.8289x over previous
//
#include <hip/hip_runtime.h>
#include <hip/hip_bf16.h>

#define B_ 256
#define L_ 225
#define D_ 1280
#define H_ 256
#define U_ 256

typedef __bf16  bf16x8 __attribute__((ext_vector_type(8)));
typedef float   f32x4  __attribute__((ext_vector_type(4)));
typedef unsigned short u16x8 __attribute__((ext_vector_type(8)));

__device__ __forceinline__ unsigned short f2bf(float f) {
    union { __hip_bfloat16 h; unsigned short u; } cv;
    cv.h = __float2bfloat16(f);   // RNE
    return cv.u;
}

__device__ __forceinline__ void gload_lds16(const void* g, void* l) {
    __builtin_amdgcn_global_load_lds(
        (const __attribute__((address_space(1))) unsigned int*)g,
        (__attribute__((address_space(3))) unsigned int*)l,
        16, 0, 0);
}

__device__ __forceinline__ float wredsum(float x) {
#pragma unroll
    for (int off = 32; off > 0; off >>= 1) x += __shfl_xor(x, off, 64);
    return x;
}

// ------ kernel 1: merged prep ------------------------------------------------
// blocks 0..79: W1 [D][U] -> w1t [U][D] bf16 via 64x64 LDS tile (coalesced
// reads AND writes). blocks 80..335: ph[b][u] = hidden[b].W2[:,u]+b1[u]+b2[u].
__global__ void k_prep(const float* __restrict__ W1,
                       const float* __restrict__ hidden,
                       const float* __restrict__ W2,
                       const float* __restrict__ b1,
                       const float* __restrict__ b2,
                       __hip_bfloat16* __restrict__ w1t,
                       float* __restrict__ ph) {
    int bid = blockIdx.x;
    if (bid < 80) {
        __shared__ float tile[64][65];
        const int kt = bid >> 2;          // 0..19 : k-tile of 64
        const int ut = bid & 3;           // 0..3  : u-tile of 64
        const int k0 = kt * 64, u0 = ut * 64;
        const int w  = threadIdx.x >> 6;  // 0..3
        const int l  = threadIdx.x & 63;
#pragma unroll
        for (int i = 0; i < 16; ++i) {
            int row = w * 16 + i;         // k within tile
            tile[row][l] = W1[(size_t)(k0 + row) * U_ + u0 + l];
        }
        __syncthreads();
#pragma unroll
        for (int i = 0; i < 16; ++i) {
            int urow = w * 16 + i;        // u within tile
            w1t[(size_t)(u0 + urow) * D_ + k0 + l] = __float2bfloat16(tile[l][urow]);
        }
    } else {
        __shared__ float sh[H_];
        int b = bid - 80;
        int u = threadIdx.x;
        sh[u] = hidden[b * H_ + u];
        __syncthreads();
        float acc = b1[u] + b2[u];
#pragma unroll 8
        for (int h = 0; h < H_; ++h) acc += sh[h] * W2[h * U_ + u];
        ph[b * U_ + u] = acc;
    }
}

// ---------------- kernel 2: fully fused per-batch kernel --------------------
// 256 blocks (1/CU) x 1024 threads. Block b: GEMM(225pad256 x 256 x 1280) ->
// tanh*V -> exp weights (no-max) -> context (f32 re-read, warm-d-first).
// LDS: dbuf 2 x 65536 (A 32K swz + B 32K swz) | sV @131072 | sPh @132096
//      sL[4][256] @133120 | sW[256] @137216 | sRed[16] @138240
__global__ __launch_bounds__(1024, 4) void k_fused(
        const float* __restrict__ feat,
        const __hip_bfloat16* __restrict__ w1t,
        const float* __restrict__ ph,
        const float* __restrict__ Vv,
        float* __restrict__ out) {
    __shared__ __align__(128) char smem[138304];
    float* sV   = (float*)(smem + 131072);
    float* sPh  = (float*)(smem + 132096);
    float* sL   = (float*)(smem + 133120);
    float* sW   = (float*)(smem + 137216);
    float* sRed = (float*)(smem + 138240);

    const int tid  = threadIdx.x;
    const int lane = tid & 63;
    const int wave = tid >> 6;     // 0..15
    const int wr   = wave >> 2;    // rows [wr*64, +64)
    const int wc   = wave & 3;     // cols [wc*64, +64)
    const int b    = blockIdx.x;

    if (tid < 256) { sV[tid] = Vv[tid]; sPh[tid] = ph[b * 256 + tid]; }

    // A staging map: thread -> (row ar, 16-float k-chunk)
    const int ar    = tid >> 2;                  // 0..255
    const int arc   = ar < L_ ? ar : (L_ - 1);   // clamp padded rows
    const int akseg = (tid & 3) << 4;            // 0,16,32,48
    const float* aSrc0 = feat + ((size_t)(b * L_ + arc) * D_ + akseg);
    const int ac80 = akseg >> 3;
    const int aswz = (ar & 7) << 4;

    f32x4 acc[4][4];
#pragma unroll
    for (int mi = 0; mi < 4; ++mi)
#pragma unroll
        for (int ni = 0; ni < 4; ++ni)
            acc[mi][ni] = (f32x4){0.f, 0.f, 0.f, 0.f};

    auto loadA = [&](int kt, f32x4* v) {
        const float* src = aSrc0 + kt * 64;
        v[0] = *reinterpret_cast<const f32x4*>(src);
        v[1] = *reinterpret_cast<const f32x4*>(src + 4);
        v[2] = *reinterpret_cast<const f32x4*>(src + 8);
        v[3] = *reinterpret_cast<const f32x4*>(src + 12);
    };
    auto stageB = [&](int kt, char* bufB) {
#pragma unroll
        for (int pass = 0; pass < 2; ++pass) {
            int s   = pass * 1024 + tid;
            int u   = s >> 3;
            int c8s = s & 7;
            int c8g = c8s ^ (u & 7);
            gload_lds16(w1t + (size_t)u * D_ + kt * 64 + c8g * 8, bufB + s * 16);
        }
    };
    auto storeA = [&](const f32x4* v, char* bufA) {
        u16x8 w0, w1;
        w0[0] = f2bf(v[0][0]); w0[1] = f2bf(v[0][1]); w0[2] = f2bf(v[0][2]); w0[3] = f2bf(v[0][3]);
        w0[4] = f2bf(v[1][0]); w0[5] = f2bf(v[1][1]); w0[6] = f2bf(v[1][2]); w0[7] = f2bf(v[1][3]);
        w1[0] = f2bf(v[2][0]); w1[1] = f2bf(v[2][1]); w1[2] = f2bf(v[2][2]); w1[3] = f2bf(v[2][3]);
        w1[4] = f2bf(v[3][0]); w1[5] = f2bf(v[3][1]); w1[6] = f2bf(v[3][2]); w1[7] = f2bf(v[3][3]);
        *reinterpret_cast<u16x8*>(bufA + (ar << 7) + ((ac80 << 4) ^ aswz))       = w0;
        *reinterpret_cast<u16x8*>(bufA + (ar << 7) + (((ac80 + 1) << 4) ^ aswz)) = w1;
    };
    auto compute = [&](const char* bufA, const char* bufB) {
#pragma unroll
        for (int ks = 0; ks < 2; ++ks) {
            const int kk2 = (ks * 32 + ((lane >> 4) << 3)) * 2;
            bf16x8 a[4], bb[4];
#pragma unroll
            for (int mi = 0; mi < 4; ++mi) {
                int r = wr * 64 + mi * 16 + (lane & 15);
                a[mi] = *reinterpret_cast<const bf16x8*>(bufA + (r << 7) + (kk2 ^ ((r & 7) << 4)));
            }
#pragma unroll
            for (int ni = 0; ni < 4; ++ni) {
                int u = wc * 64 + ni * 16 + (lane & 15);
                bb[ni] = *reinterpret_cast<const bf16x8*>(bufB + (u << 7) + (kk2 ^ ((u & 7) << 4)));
            }
#pragma unroll
            for (int mi = 0; mi < 4; ++mi)
#pragma unroll
                for (int ni = 0; ni < 4; ++ni)
                    acc[mi][ni] = __builtin_amdgcn_mfma_f32_16x16x32_bf16(
                        a[mi], bb[ni], acc[mi][ni], 0, 0, 0);
        }
    };

    // ---- phase 1: K-streamed GEMM, dbuf, T14 split (load early, write late)
    {
        f32x4 v[4];
        loadA(0, v);
        stageB(0, smem + 32768);
        storeA(v, smem);
    }
    __syncthreads();
    int cur = 0;
    for (int kt = 0; kt < 20; ++kt) {
        char* bufN = smem + (cur ^ 1) * 65536;
        f32x4 v[4];
        if (kt < 19) { loadA(kt + 1, v); stageB(kt + 1, bufN + 32768); }
        char* bufC = smem + cur * 65536;
        compute(bufC, bufC + 32768);
        if (kt < 19) storeA(v, bufN);
        __syncthreads();
        cur ^= 1;
    }

    // ---- epilogue: tanh(acc+ph)*V -> logits; w = exp(logit) (no max) ----
    float phu[4], vu[4];
#pragma unroll
    for (int ni = 0; ni < 4; ++ni) {
        int u = wc * 64 + ni * 16 + (lane & 15);
        phu[ni] = sPh[u];
        vu[ni]  = sV[u];
    }
#pragma unroll
    for (int mi = 0; mi < 4; ++mi) {
#pragma unroll
        for (int rg = 0; rg < 4; ++rg) {
            int row = wr * 64 + mi * 16 + ((lane >> 4) << 2) + rg;
            float s = 0.f;
#pragma unroll
            for (int ni = 0; ni < 4; ++ni) {
                float x = acc[mi][ni][rg] + phu[ni];
                s += (1.f - 2.f / (__expf(2.f * x) + 1.f)) * vu[ni];
            }
            s += __shfl_xor(s, 1, 64);
            s += __shfl_xor(s, 2, 64);
            s += __shfl_xor(s, 4, 64);
            s += __shfl_xor(s, 8, 64);
            if ((lane & 15) == 0) sL[wc * 256 + row] = s;
        }
    }
    __syncthreads();
    float den_p = 0.f;
    if (tid < 256) {
        float lg = sL[tid] + sL[256 + tid] + sL[512 + tid] + sL[768 + tid];
        float w  = (tid < L_) ? __expf(lg) : 0.f;   // |lg| <= sum|V| ~ 13: safe
        sW[tid] = w;
        den_p = w;
    }
    den_p = wredsum(den_p);
    if (lane == 0) sRed[wave] = den_p;
    __syncthreads();

    // ---- phase 3: context, warm-d-first (chs 1-4 are L3-resident from the
    //      tail of the phase-1 k-ascending stream; ch 0 is the cold pass) ----
    f32x4 c[5];
#pragma unroll
    for (int ch = 0; ch < 5; ++ch) c[ch] = (f32x4){0.f, 0.f, 0.f, 0.f};
    {
        const float* fB = feat + (size_t)b * L_ * D_ + (lane << 2);
        // pass A: warm chunks (d >= 256)
        for (int l = wave; l < L_; l += 16) {
            float wa = sW[l];
            const float* ra = fB + (size_t)l * D_;
#pragma unroll
            for (int ch = 1; ch < 5; ++ch)
                c[ch] += wa * *reinterpret_cast<const f32x4*>(ra + ch * 256);
        }
        // pass B: cold chunk (d < 256)
        for (int l = wave; l < L_; l += 16) {
            c[0] += sW[l] * *reinterpret_cast<const f32x4*>(fB + (size_t)l * D_);
        }
    }

    // ---- final: reduce 16 wave partials, divide by den, write out ----
    float* pc = (float*)smem;   // [16][1280] f32, reuses dbuf region
#pragma unroll
    for (int ch = 0; ch < 5; ++ch)
        *reinterpret_cast<f32x4*>(pc + wave * 1280 + ch * 256 + (lane << 2)) = c[ch];
    __syncthreads();
    if (tid < 320) {
        f32x4 s = (f32x4){0.f, 0.f, 0.f, 0.f};
#pragma unroll
        for (int w = 0; w < 16; ++w)
            s += *reinterpret_cast<const f32x4*>(pc + w * 1280 + (tid << 2));
        float den = 0.f;
#pragma unroll
        for (int i = 0; i < 16; ++i) den += sRed[i];
        s *= (1.f / den);
        *reinterpret_cast<f32x4*>(out + (size_t)b * D_ + (tid << 2)) = s;
    }
}

extern "C" void kernel_launch(void* const* d_in, const int* in_sizes, int n_in,
                              void* d_out, int out_size, void* d_ws, size_t ws_size,
                              hipStream_t stream) {
    const float* feat   = (const float*)d_in[0];
    const float* hidden = (const float*)d_in[1];
    const float* W1     = (const float*)d_in[2];
    const float* b1     = (const float*)d_in[3];
    const float* W2     = (const float*)d_in[4];
    const float* b2     = (const float*)d_in[5];
    const float* Vv     = (const float*)d_in[6];
    // bV (d_in[7]) is a uniform logit shift -> softmax-invariant; skipped.

    char* ws = (char*)d_ws;
    __hip_bfloat16* w1t = (__hip_bfloat16*)(ws);        // 655360 B
    float* ph = (float*)(ws + 655360);                  // 262144 B
    float* out = (float*)d_out;

    k_prep <<<336, 256, 0, stream>>>(W1, hidden, W2, b1, b2, w1t, ph);
    k_fused<<<B_, 1024, 0, stream>>>(feat, w1t, ph, Vv, out);
}

// Round 13
// 123.416 us; speedup vs baseline: 1.8797x; 1.0277x over previous
//
#include <hip/hip_runtime.h>
#include <hip/hip_bf16.h>

#define B_ 256
#define L_ 225
#define D_ 1280
#define H_ 256
#define U_ 256
#define BM 128

typedef __bf16  bf16x8 __attribute__((ext_vector_type(8)));
typedef float   f32x4  __attribute__((ext_vector_type(4)));
typedef unsigned short u16x8 __attribute__((ext_vector_type(8)));

__device__ __forceinline__ unsigned short f2bf(float f) {
    union { __hip_bfloat16 h; unsigned short u; } cv;
    cv.h = __float2bfloat16(f);   // RNE
    return cv.u;
}

__device__ __forceinline__ void gload_lds16(const void* g, void* l) {
    __builtin_amdgcn_global_load_lds(
        (const __attribute__((address_space(1))) unsigned int*)g,
        (__attribute__((address_space(3))) unsigned int*)l,
        16, 0, 0);
}

__device__ __forceinline__ float wredsum(float x) {
#pragma unroll
    for (int off = 32; off > 0; off >>= 1) x += __shfl_xor(x, off, 64);
    return x;
}

// ------ kernel 1: merged prep (R12, unchanged) -------------------------------
__global__ void k_prep(const float* __restrict__ W1,
                       const float* __restrict__ hidden,
                       const float* __restrict__ W2,
                       const float* __restrict__ b1,
                       const float* __restrict__ b2,
                       __hip_bfloat16* __restrict__ w1t,
                       float* __restrict__ ph) {
    int bid = blockIdx.x;
    if (bid < 80) {
        __shared__ float tile[64][65];
        const int kt = bid >> 2;
        const int ut = bid & 3;
        const int k0 = kt * 64, u0 = ut * 64;
        const int w  = threadIdx.x >> 6;
        const int l  = threadIdx.x & 63;
#pragma unroll
        for (int i = 0; i < 16; ++i) {
            int row = w * 16 + i;
            tile[row][l] = W1[(size_t)(k0 + row) * U_ + u0 + l];
        }
        __syncthreads();
#pragma unroll
        for (int i = 0; i < 16; ++i) {
            int urow = w * 16 + i;
            w1t[(size_t)(u0 + urow) * D_ + k0 + l] = __float2bfloat16(tile[l][urow]);
        }
    } else {
        __shared__ float sh[H_];
        int b = bid - 80;
        int u = threadIdx.x;
        sh[u] = hidden[b * H_ + u];
        __syncthreads();
        float acc = b1[u] + b2[u];
#pragma unroll 8
        for (int h = 0; h < H_; ++h) acc += sh[h] * W2[h * U_ + u];
        ph[b * U_ + u] = acc;
    }
}

// ---------------- kernel 2: half-batch fused kernel, 2 blocks/CU ------------
// 512 blocks (b = blk>>1, half h = blk&1) x 512 threads (8 waves, 2x4).
// GEMM(113pad128 x 256 x 1280, BK=64, single-buffered 48KB) -> tanh*V ->
// exp weights (own rows only; softmax den crosses halves via k_out) ->
// ctx partial from own rows (self-warm re-read) -> num/den partials.
// LDS: sA@0 16K | sB@16384 32K | sV@49152 | sPh@50176 | sL[4][128]@51200
//      sW[128]@53248 | sRed[2]@53760 -> ~54KB => 2 blocks/CU.
__global__ __launch_bounds__(512, 4) void k_fused(
        const float* __restrict__ feat,
        const __hip_bfloat16* __restrict__ w1t,
        const float* __restrict__ ph,
        const float* __restrict__ Vv,
        float* __restrict__ num,
        float* __restrict__ den) {
    __shared__ __align__(128) char smem[53768];
    char*  sA  = smem;
    char*  sB  = smem + 16384;
    float* sV  = (float*)(smem + 49152);
    float* sPh = (float*)(smem + 50176);
    float* sL  = (float*)(smem + 51200);
    float* sW  = (float*)(smem + 53248);
    float* sRed= (float*)(smem + 53760);

    const int tid  = threadIdx.x;
    const int lane = tid & 63;
    const int wave = tid >> 6;     // 0..7
    const int wr   = wave >> 2;    // rows [wr*64, +64)
    const int wc   = wave & 3;     // cols [wc*64, +64)
    const int blk  = blockIdx.x;
    const int b    = blk >> 1;
    const int h    = blk & 1;
    const int l0   = h * 113;
    const int nl   = h ? 112 : 113;

    if (tid < 256) { sV[tid] = Vv[tid]; sPh[tid] = ph[b * 256 + tid]; }

    const float* featH = feat + ((size_t)b * L_ + l0) * D_;

    // A staging map: thread -> (row ar 0..127, 16-float k-chunk)
    const int ar    = tid >> 2;
    const int arc   = ar < nl ? ar : (nl - 1);
    const int akseg = (tid & 3) << 4;            // 0,16,32,48
    const float* aSrc0 = featH + (size_t)arc * D_ + akseg;
    const int ac80 = akseg >> 3;
    const int aswz = (ar & 7) << 4;

    f32x4 acc[4][4];
#pragma unroll
    for (int mi = 0; mi < 4; ++mi)
#pragma unroll
        for (int ni = 0; ni < 4; ++ni)
            acc[mi][ni] = (f32x4){0.f, 0.f, 0.f, 0.f};

    // ---- phase 1: K-loop, single-buffered, 2 barriers/step ----
    for (int kt = 0; kt < 20; ++kt) {
        // A-loads issued before barrier-1 (T14: latency hides under drain)
        const float* src = aSrc0 + kt * 64;
        f32x4 v0 = *reinterpret_cast<const f32x4*>(src);
        f32x4 v1 = *reinterpret_cast<const f32x4*>(src + 4);
        f32x4 v2 = *reinterpret_cast<const f32x4*>(src + 8);
        f32x4 v3 = *reinterpret_cast<const f32x4*>(src + 12);
        __syncthreads();   // prior compute done; buffers writable
        // B: 4 chunks/thread via global_load_lds (linear dest, pre-swz src)
#pragma unroll
        for (int p = 0; p < 4; ++p) {
            int sI = p * 512 + tid;            // 0..2047
            int u  = sI >> 3;
            int c8 = (sI & 7) ^ (u & 7);
            gload_lds16(w1t + (size_t)u * D_ + kt * 64 + c8 * 8, sB + sI * 16);
        }
        // A: cvt + swizzled store
        {
            u16x8 w0, w1;
            w0[0] = f2bf(v0[0]); w0[1] = f2bf(v0[1]); w0[2] = f2bf(v0[2]); w0[3] = f2bf(v0[3]);
            w0[4] = f2bf(v1[0]); w0[5] = f2bf(v1[1]); w0[6] = f2bf(v1[2]); w0[7] = f2bf(v1[3]);
            w1[0] = f2bf(v2[0]); w1[1] = f2bf(v2[1]); w1[2] = f2bf(v2[2]); w1[3] = f2bf(v2[3]);
            w1[4] = f2bf(v3[0]); w1[5] = f2bf(v3[1]); w1[6] = f2bf(v3[2]); w1[7] = f2bf(v3[3]);
            *reinterpret_cast<u16x8*>(sA + (ar << 7) + ((ac80 << 4) ^ aswz))       = w0;
            *reinterpret_cast<u16x8*>(sA + (ar << 7) + (((ac80 + 1) << 4) ^ aswz)) = w1;
        }
        __syncthreads();   // staged tile visible (vmcnt drained by compiler)

#pragma unroll
        for (int ks = 0; ks < 2; ++ks) {
            const int kk2 = (ks * 32 + ((lane >> 4) << 3)) * 2;
            bf16x8 a[4], bb[4];
#pragma unroll
            for (int mi = 0; mi < 4; ++mi) {
                int r = wr * 64 + mi * 16 + (lane & 15);
                a[mi] = *reinterpret_cast<const bf16x8*>(sA + (r << 7) + (kk2 ^ ((r & 7) << 4)));
            }
#pragma unroll
            for (int ni = 0; ni < 4; ++ni) {
                int u = wc * 64 + ni * 16 + (lane & 15);
                bb[ni] = *reinterpret_cast<const bf16x8*>(sB + (u << 7) + (kk2 ^ ((u & 7) << 4)));
            }
#pragma unroll
            for (int mi = 0; mi < 4; ++mi)
#pragma unroll
                for (int ni = 0; ni < 4; ++ni)
                    acc[mi][ni] = __builtin_amdgcn_mfma_f32_16x16x32_bf16(
                        a[mi], bb[ni], acc[mi][ni], 0, 0, 0);
        }
    }
    __syncthreads();   // last LDS reads done before sL writes

    // ---- epilogue: tanh(acc+ph)*V -> per-colgroup partial logits ----
    float phu[4], vu[4];
#pragma unroll
    for (int ni = 0; ni < 4; ++ni) {
        int u = wc * 64 + ni * 16 + (lane & 15);
        phu[ni] = sPh[u];
        vu[ni]  = sV[u];
    }
#pragma unroll
    for (int mi = 0; mi < 4; ++mi) {
#pragma unroll
        for (int rg = 0; rg < 4; ++rg) {
            int row = wr * 64 + mi * 16 + ((lane >> 4) << 2) + rg;   // 0..127
            float s = 0.f;
#pragma unroll
            for (int ni = 0; ni < 4; ++ni) {
                float x = acc[mi][ni][rg] + phu[ni];
                s += (1.f - 2.f / (__expf(2.f * x) + 1.f)) * vu[ni];
            }
            s += __shfl_xor(s, 1, 64);
            s += __shfl_xor(s, 2, 64);
            s += __shfl_xor(s, 4, 64);
            s += __shfl_xor(s, 8, 64);
            if ((lane & 15) == 0) sL[wc * 128 + row] = s;
        }
    }
    __syncthreads();

    // ---- weights w = exp(logit) for own rows; partial denominator ----
    if (tid < 128) {
        float lg = sL[tid] + sL[128 + tid] + sL[256 + tid] + sL[384 + tid];
        float w  = (tid < nl) ? __expf(lg) : 0.f;   // |lg| <= sum|V| ~ 13
        sW[tid] = w;
        float d = wredsum(w);
        if ((tid & 63) == 0) sRed[tid >> 6] = d;
    }
    __syncthreads();

    // ---- phase 3: ctx partial from own rows (self-warm), warm-d-first ----
    f32x4 c[5];
#pragma unroll
    for (int ch = 0; ch < 5; ++ch) c[ch] = (f32x4){0.f, 0.f, 0.f, 0.f};
    {
        const float* fB = featH + (lane << 2);
        for (int l = wave; l < nl; l += 8) {       // pass A: warm (d >= 256)
            float wa = sW[l];
            const float* ra = fB + (size_t)l * D_;
#pragma unroll
            for (int ch = 1; ch < 5; ++ch)
                c[ch] += wa * *reinterpret_cast<const f32x4*>(ra + ch * 256);
        }
        for (int l = wave; l < nl; l += 8)         // pass B: cold (d < 256)
            c[0] += sW[l] * *reinterpret_cast<const f32x4*>(fB + (size_t)l * D_);
    }
    __syncthreads();   // sL/sW reads done; GEMM LDS region free

    // ---- reduce 8 wave partials -> num[blk]; den[blk] ----
    float* pc = (float*)smem;   // [8][1280] f32 = 40KB (below sV @49152)
#pragma unroll
    for (int ch = 0; ch < 5; ++ch)
        *reinterpret_cast<f32x4*>(pc + wave * 1280 + ch * 256 + (lane << 2)) = c[ch];
    __syncthreads();
    if (tid < 320) {
        f32x4 s = (f32x4){0.f, 0.f, 0.f, 0.f};
#pragma unroll
        for (int w = 0; w < 8; ++w)
            s += *reinterpret_cast<const f32x4*>(pc + w * 1280 + (tid << 2));
        *reinterpret_cast<f32x4*>(num + (size_t)blk * 1280 + (tid << 2)) = s;
    }
    if (tid == 0) den[blk] = sRed[0] + sRed[1];
}

// ---------------- kernel 3: combine halves, divide ---------------------------
__global__ void k_out(const float* __restrict__ num, const float* __restrict__ den,
                      float* __restrict__ out) {
    int b = blockIdx.x;
    int t = threadIdx.x;   // 0..319
    f32x4 s = *reinterpret_cast<const f32x4*>(num + (size_t)(b * 2) * D_ + (t << 2))
            + *reinterpret_cast<const f32x4*>(num + (size_t)(b * 2 + 1) * D_ + (t << 2));
    s *= (1.f / (den[b * 2] + den[b * 2 + 1]));
    *reinterpret_cast<f32x4*>(out + (size_t)b * D_ + (t << 2)) = s;
}

extern "C" void kernel_launch(void* const* d_in, const int* in_sizes, int n_in,
                              void* d_out, int out_size, void* d_ws, size_t ws_size,
                              hipStream_t stream) {
    const float* feat   = (const float*)d_in[0];
    const float* hidden = (const float*)d_in[1];
    const float* W1     = (const float*)d_in[2];
    const float* b1     = (const float*)d_in[3];
    const float* W2     = (const float*)d_in[4];
    const float* b2     = (const float*)d_in[5];
    const float* Vv     = (const float*)d_in[6];
    // bV (d_in[7]) is a uniform logit shift -> softmax-invariant; skipped.

    char* ws = (char*)d_ws;
    __hip_bfloat16* w1t = (__hip_bfloat16*)(ws);    // 655360 B
    float* ph  = (float*)(ws + 655360);             // 262144 B
    float* num = (float*)(ws + 917504);             // 512*1280*4 = 2621440 B
    float* den = (float*)(ws + 3538944);            // 2048 B
    float* out = (float*)d_out;

    k_prep <<<336, 256, 0, stream>>>(W1, hidden, W2, b1, b2, w1t, ph);
    k_fused<<<B_ * 2, 512, 0, stream>>>(feat, w1t, ph, Vv, num, den);
    k_out  <<<B_, 320, 0, stream>>>(num, den, out);
}